// Round 1
// baseline (554.950 us; speedup 1.0000x reference)
//
#include <hip/hip_runtime.h>

#define K_ 20
#define KD_ 128
#define HID_ 256
#define NKP_ 100

__global__ __launch_bounds__(256) void cdm_fwd(
    const int* __restrict__ stu_idx,
    const int* __restrict__ kp_idx,
    const int* __restrict__ kp_len,
    const float* __restrict__ emb,
    const float* __restrict__ W1,
    const float* __restrict__ b1,
    const float* __restrict__ w2,
    const float* __restrict__ b2,
    const float* __restrict__ M1,
    const float* __restrict__ mb1,
    const float* __restrict__ M2,
    const float* __restrict__ mb2,
    const float* __restrict__ M3,
    const float* __restrict__ mb3,
    float* __restrict__ out_scores,
    float* __restrict__ out_att)
{
    const int b = blockIdx.x;
    const int tid = threadIdx.x;
    const int lane = tid & 63;
    const int wid = tid >> 6;

    __shared__ float vec[K_][KD_];      // 10 KB
    __shared__ float red[4][K_];
    __shared__ float att_s[K_];
    __shared__ float weighted[KD_];
    __shared__ float h1[HID_];
    __shared__ float h2[KD_];
    __shared__ int   kp_s[K_];

    const int len = kp_len[b];
    const long long base = (long long)stu_idx[b] * (long long)(NKP_ * KD_);

    if (tid < K_) kp_s[tid] = kp_idx[b * K_ + tid];
    __syncthreads();

    // ---- gather vecs (masked rows -> 0), 20 rows x 128 f32 ----
    for (int i = tid; i < K_ * KD_; i += 256) {
        const int k = i >> 7;
        const int d = i & (KD_ - 1);
        float v = 0.f;
        if (k < len) {
            v = emb[base + (long long)kp_s[k] * KD_ + d];
        }
        vec[k][d] = v;
    }
    __syncthreads();

    // ---- tanh attention layer: acc[k] = vec[k,:] @ W1[:, tid] ----
    float acc[K_];
#pragma unroll
    for (int k = 0; k < K_; ++k) acc[k] = 0.f;

    for (int d = 0; d < KD_; d += 4) {
        const float wa = W1[(d + 0) * HID_ + tid];
        const float wb = W1[(d + 1) * HID_ + tid];
        const float wc = W1[(d + 2) * HID_ + tid];
        const float wd = W1[(d + 3) * HID_ + tid];
#pragma unroll
        for (int k = 0; k < K_; ++k) {
            const float4 v = *(const float4*)&vec[k][d];
            acc[k] = fmaf(v.x, wa, acc[k]);
            acc[k] = fmaf(v.y, wb, acc[k]);
            acc[k] = fmaf(v.z, wc, acc[k]);
            acc[k] = fmaf(v.w, wd, acc[k]);
        }
    }

    const float b1v = b1[tid];
    const float w2v = w2[tid];
#pragma unroll
    for (int k = 0; k < K_; ++k) {
        float p = tanhf(acc[k] + b1v) * w2v;
        p += __shfl_down(p, 32);
        p += __shfl_down(p, 16);
        p += __shfl_down(p, 8);
        p += __shfl_down(p, 4);
        p += __shfl_down(p, 2);
        p += __shfl_down(p, 1);
        if (lane == 0) red[wid][k] = p;
    }
    __syncthreads();

    // ---- softmax over all K (masked rows contribute their zero-vec logit) ----
    if (tid == 0) {
        const float b2v = b2[0];
        float l[K_], m = -1e30f;
#pragma unroll
        for (int k = 0; k < K_; ++k) {
            l[k] = red[0][k] + red[1][k] + red[2][k] + red[3][k] + b2v;
            m = fmaxf(m, l[k]);
        }
        float s = 0.f;
#pragma unroll
        for (int k = 0; k < K_; ++k) { l[k] = expf(l[k] - m); s += l[k]; }
        const float inv = 1.f / s;
#pragma unroll
        for (int k = 0; k < K_; ++k) att_s[k] = (k < len) ? l[k] * inv : 0.f;
    }
    __syncthreads();

    // ---- write att output; weighted sum over k ----
    if (tid < K_) out_att[b * K_ + tid] = att_s[tid];
    if (tid < KD_) {
        float s = 0.f;
#pragma unroll
        for (int k = 0; k < K_; ++k) s = fmaf(att_s[k], vec[k][tid], s);
        weighted[tid] = s;
    }
    __syncthreads();

    // ---- layer1: h1 = relu(weighted @ M1 + mb1) (256 outs) ----
    float a1 = mb1[tid];
    for (int d = 0; d < KD_; d += 4) {
        const float4 v = *(const float4*)&weighted[d];
        a1 = fmaf(v.x, M1[(d + 0) * HID_ + tid], a1);
        a1 = fmaf(v.y, M1[(d + 1) * HID_ + tid], a1);
        a1 = fmaf(v.z, M1[(d + 2) * HID_ + tid], a1);
        a1 = fmaf(v.w, M1[(d + 3) * HID_ + tid], a1);
    }
    h1[tid] = fmaxf(a1, 0.f);
    __syncthreads();

    // ---- layer2: h2 = relu(h1 @ M2 + mb2) (128 outs) ----
    if (tid < KD_) {
        float a2 = mb2[tid];
        for (int j = 0; j < HID_; j += 4) {
            const float4 v = *(const float4*)&h1[j];
            a2 = fmaf(v.x, M2[(j + 0) * KD_ + tid], a2);
            a2 = fmaf(v.y, M2[(j + 1) * KD_ + tid], a2);
            a2 = fmaf(v.z, M2[(j + 2) * KD_ + tid], a2);
            a2 = fmaf(v.w, M2[(j + 3) * KD_ + tid], a2);
        }
        h2[tid] = fmaxf(a2, 0.f);
    }
    __syncthreads();

    // ---- layer3: score = sigmoid(h2 @ M3 + mb3) ----
    if (tid < 64) {
        float p = fmaf(h2[tid], M3[tid], h2[tid + 64] * M3[tid + 64]);
        p += __shfl_down(p, 32);
        p += __shfl_down(p, 16);
        p += __shfl_down(p, 8);
        p += __shfl_down(p, 4);
        p += __shfl_down(p, 2);
        p += __shfl_down(p, 1);
        if (tid == 0) out_scores[b] = 1.f / (1.f + expf(-(p + mb3[0])));
    }
}

extern "C" void kernel_launch(void* const* d_in, const int* in_sizes, int n_in,
                              void* d_out, int out_size, void* d_ws, size_t ws_size,
                              hipStream_t stream) {
    const int*   stu = (const int*)d_in[0];
    const int*   kpi = (const int*)d_in[1];
    const int*   kpl = (const int*)d_in[2];
    const float* emb = (const float*)d_in[3];
    const float* W1  = (const float*)d_in[4];
    const float* b1  = (const float*)d_in[5];
    const float* w2  = (const float*)d_in[6];
    const float* b2  = (const float*)d_in[7];
    const float* M1  = (const float*)d_in[8];
    const float* mb1 = (const float*)d_in[9];
    const float* M2  = (const float*)d_in[10];
    const float* mb2 = (const float*)d_in[11];
    const float* M3  = (const float*)d_in[12];
    const float* mb3 = (const float*)d_in[13];
    const int B = in_sizes[0];

    float* out_scores = (float*)d_out;
    float* out_att    = out_scores + B;

    cdm_fwd<<<B, 256, 0, stream>>>(stu, kpi, kpl, emb, W1, b1, w2, b2,
                                   M1, mb1, M2, mb2, M3, mb3,
                                   out_scores, out_att);
}

// Round 2
// 189.994 us; speedup vs baseline: 2.9209x; 2.9209x over previous
//
#include <hip/hip_runtime.h>
#include <hip/hip_bf16.h>

#define K_ 20
#define KD_ 128
#define HID_ 256
#define NKP_ 100
#define SPB 4

using short8_t = __attribute__((ext_vector_type(8))) short;
using f32x4 = __attribute__((ext_vector_type(4))) float;

__device__ __forceinline__ unsigned short f2bf(float f) {
    __hip_bfloat16 h = __float2bfloat16(f);
    return *reinterpret_cast<unsigned short*>(&h);
}

// W1 [128][256] f32 -> frag-major bf16: frag(n,s), lane l, elem j holds
// W1[k = s*32 + (l>>4)*8 + j][col = n*16 + (l&15)].  16KB-coalesced loads later.
__global__ __launch_bounds__(256) void prep_w1(const float* __restrict__ W1,
                                               unsigned short* __restrict__ out) {
    const int i = blockIdx.x * 256 + threadIdx.x;   // 0..32767
    const int j = i & 7;
    const int l = (i >> 3) & 63;
    const int s = (i >> 9) & 3;
    const int n = i >> 11;
    const int k = s * 32 + (l >> 4) * 8 + j;
    const int col = n * 16 + (l & 15);
    out[i] = f2bf(W1[k * HID_ + col]);
}

__device__ __forceinline__ float fast_tanh(float x) {
    // 1 - 2/(e^{2x}+1): monotone, saturates to +-1 without NaN at |x| large
    return 1.f - 2.f / (__expf(2.f * x) + 1.f);
}

__global__ __launch_bounds__(256) void cdm_fwd(
    const int* __restrict__ stu_idx,
    const int* __restrict__ kp_idx,
    const int* __restrict__ kp_len,
    const float* __restrict__ emb,
    const unsigned short* __restrict__ w1f,
    const float* __restrict__ b1,
    const float* __restrict__ w2,
    const float* __restrict__ b2,
    const float* __restrict__ M1,
    const float* __restrict__ mb1,
    const float* __restrict__ M2,
    const float* __restrict__ mb2,
    const float* __restrict__ M3,
    const float* __restrict__ mb3,
    float* __restrict__ out_scores,
    float* __restrict__ out_att)
{
    const int tid  = threadIdx.x;
    const int lane = tid & 63;
    const int wid  = tid >> 6;                 // wave owns sample wid
    const int gs   = blockIdx.x * SPB + wid;   // global sample

    __shared__ unsigned short vec_s[SPB][32][KD_]; // 32 KB, XOR-swizzled rows
    __shared__ float logit_s[SPB][K_];
    __shared__ float att_s[SPB][K_];
    __shared__ float wsum_s[SPB][KD_];
    __shared__ float h1_s[SPB][HID_];
    __shared__ float h2_s[SPB][HID_ / 2];

    const int len = kp_len[gs];

    // ---------- gather: emb rows -> bf16 LDS (rows >= len and pad rows 20..31 -> 0) ----------
    {
        const int r    = lane >> 1;   // 0..31
        const int half = lane & 1;    // which 64-float half of the row
        const bool valid = (r < K_) && (r < len);
        const float* src = nullptr;
        if (valid) {
            const long long base = (long long)stu_idx[gs] * (long long)(NKP_ * KD_);
            const int kp = kp_idx[gs * K_ + r];
            src = emb + base + (long long)kp * KD_ + half * 64;
        }
        float4 v[16];
#pragma unroll
        for (int i = 0; i < 16; ++i)
            v[i] = valid ? ((const float4*)src)[i] : make_float4(0.f, 0.f, 0.f, 0.f);

        char* vb = (char*)&vec_s[wid][0][0];
#pragma unroll
        for (int c = 0; c < 8; ++c) {
            short8_t pk;
            const float4 a = v[2 * c], bq = v[2 * c + 1];
            pk[0] = (short)f2bf(a.x);  pk[1] = (short)f2bf(a.y);
            pk[2] = (short)f2bf(a.z);  pk[3] = (short)f2bf(a.w);
            pk[4] = (short)f2bf(bq.x); pk[5] = (short)f2bf(bq.y);
            pk[6] = (short)f2bf(bq.z); pk[7] = (short)f2bf(bq.w);
            const int off = r * 256 + ((half * 128 + c * 16) ^ ((r & 7) << 4));
            *(short8_t*)(vb + off) = pk;
        }
    }
    __syncthreads();

    // ---------- A-fragments from LDS (swizzled, conflict-free ds_read_b128) ----------
    short8_t A[2][4];
    {
        const char* vb = (const char*)&vec_s[wid][0][0];
#pragma unroll
        for (int m = 0; m < 2; ++m)
#pragma unroll
            for (int s = 0; s < 4; ++s) {
                const int off = (m * 16 + (lane & 15)) * 256 +
                                ((s * 64 + (lane >> 4) * 16) ^ ((lane & 7) << 4));
                A[m][s] = *(const short8_t*)(vb + off);
            }
    }

    // ---------- MFMA P = vec @ W1, fused tanh*w2 epilogue into logit partials ----------
    float lp[8];
#pragma unroll
    for (int i = 0; i < 8; ++i) lp[i] = 0.f;
    const int colbase = lane & 15;
    const short8_t* bfr = (const short8_t*)w1f;
#pragma unroll 4
    for (int n = 0; n < 16; ++n) {
        f32x4 a0 = {0.f, 0.f, 0.f, 0.f}, a1 = {0.f, 0.f, 0.f, 0.f};
#pragma unroll
        for (int s = 0; s < 4; ++s) {
            const short8_t Bs = bfr[(n * 4 + s) * 64 + lane];
            a0 = __builtin_amdgcn_mfma_f32_16x16x32_bf16(A[0][s], Bs, a0, 0, 0, 0);
            a1 = __builtin_amdgcn_mfma_f32_16x16x32_bf16(A[1][s], Bs, a1, 0, 0, 0);
        }
        const float b1v = b1[n * 16 + colbase];
        const float w2v = w2[n * 16 + colbase];
#pragma unroll
        for (int i = 0; i < 4; ++i) {
            lp[i]     += fast_tanh(a0[i] + b1v) * w2v;
            lp[4 + i] += fast_tanh(a1[i] + b1v) * w2v;
        }
    }
    // reduce over the 16 columns each lane-group covers
#pragma unroll
    for (int i = 0; i < 8; ++i) {
        lp[i] += __shfl_xor(lp[i], 1);
        lp[i] += __shfl_xor(lp[i], 2);
        lp[i] += __shfl_xor(lp[i], 4);
        lp[i] += __shfl_xor(lp[i], 8);
    }
    const float b2v = b2[0];
    if ((lane & 15) == 0) {
        const int rbase = (lane >> 4) * 4;       // rows 0..15 (m-tile 0)
#pragma unroll
        for (int i = 0; i < 4; ++i) logit_s[wid][rbase + i] = lp[i] + b2v;
    }
    if (lane == 0) {                              // rows 16..19 (m-tile 1)
#pragma unroll
        for (int i = 0; i < 4; ++i) logit_s[wid][16 + i] = lp[4 + i] + b2v;
    }
    __syncthreads();

    // ---------- softmax over all K (reference semantics), mask applied to att ----------
    {
        float m = -1e30f;
#pragma unroll
        for (int k = 0; k < K_; ++k) m = fmaxf(m, logit_s[wid][k]);
        float ssum = 0.f;
#pragma unroll
        for (int k = 0; k < K_; ++k) ssum += __expf(logit_s[wid][k] - m);
        const float rs = 1.f / ssum;
        if (lane < K_) {
            const float a = (lane < len) ? __expf(logit_s[wid][lane] - m) * rs : 0.f;
            att_s[wid][lane] = a;
            out_att[gs * K_ + lane] = a;
        }
    }
    __syncthreads();

    // ---------- weighted = sum_k att_k * vec_k  (each lane owns 2 d's) ----------
    {
        const char* vb = (const char*)&vec_s[wid][0][0];
        const int d0 = lane * 2;
        float s0 = 0.f, s1 = 0.f;
#pragma unroll
        for (int k = 0; k < K_; ++k) {
            const unsigned int u = *(const unsigned int*)(vb + k * 256 + ((lane * 4) ^ ((k & 7) << 4)));
            const float av = att_s[wid][k];
            s0 += av * __uint_as_float(u << 16);
            s1 += av * __uint_as_float(u & 0xffff0000u);
        }
        wsum_s[wid][d0] = s0;
        wsum_s[wid][d0 + 1] = s1;
    }
    __syncthreads();

    // ---------- M1: h1 = relu(weighted @ M1 + mb1), block-wide (M1 fetched once) ----------
    {
        float acc[SPB];
        const float bias = mb1[tid];
#pragma unroll
        for (int s = 0; s < SPB; ++s) acc[s] = bias;
        for (int d = 0; d < KD_; d += 4) {
            const float m0 = M1[(d + 0) * HID_ + tid];
            const float m1 = M1[(d + 1) * HID_ + tid];
            const float m2 = M1[(d + 2) * HID_ + tid];
            const float m3 = M1[(d + 3) * HID_ + tid];
#pragma unroll
            for (int s = 0; s < SPB; ++s) {
                const float4 w = *(const float4*)&wsum_s[s][d];
                acc[s] += w.x * m0 + w.y * m1 + w.z * m2 + w.w * m3;
            }
        }
#pragma unroll
        for (int s = 0; s < SPB; ++s) h1_s[s][tid] = fmaxf(acc[s], 0.f);
    }
    __syncthreads();

    // ---------- M2: h2 = relu(h1 @ M2 + mb2), 128 cols x 4 samples over 256 threads ----------
    {
        const int c = tid & 127;
        const int g = tid >> 7;    // samples {0,1} or {2,3}
        float acc0 = mb2[c], acc1 = acc0;
        for (int h = 0; h < HID_; h += 4) {
            const float m0 = M2[(h + 0) * (HID_ / 2) + c];
            const float m1 = M2[(h + 1) * (HID_ / 2) + c];
            const float m2 = M2[(h + 2) * (HID_ / 2) + c];
            const float m3 = M2[(h + 3) * (HID_ / 2) + c];
            const float4 ha = *(const float4*)&h1_s[2 * g + 0][h];
            const float4 hb = *(const float4*)&h1_s[2 * g + 1][h];
            acc0 += ha.x * m0 + ha.y * m1 + ha.z * m2 + ha.w * m3;
            acc1 += hb.x * m0 + hb.y * m1 + hb.z * m2 + hb.w * m3;
        }
        h2_s[2 * g + 0][c] = fmaxf(acc0, 0.f);
        h2_s[2 * g + 1][c] = fmaxf(acc1, 0.f);
    }
    __syncthreads();

    // ---------- M3 + sigmoid ----------
    {
        float p = h2_s[wid][lane] * M3[lane] + h2_s[wid][lane + 64] * M3[lane + 64];
        p += __shfl_down(p, 32); p += __shfl_down(p, 16); p += __shfl_down(p, 8);
        p += __shfl_down(p, 4);  p += __shfl_down(p, 2);  p += __shfl_down(p, 1);
        if (lane == 0) out_scores[gs] = 1.f / (1.f + __expf(-(p + mb3[0])));
    }
}

extern "C" void kernel_launch(void* const* d_in, const int* in_sizes, int n_in,
                              void* d_out, int out_size, void* d_ws, size_t ws_size,
                              hipStream_t stream) {
    const int*   stu = (const int*)d_in[0];
    const int*   kpi = (const int*)d_in[1];
    const int*   kpl = (const int*)d_in[2];
    const float* emb = (const float*)d_in[3];
    const float* W1  = (const float*)d_in[4];
    const float* b1  = (const float*)d_in[5];
    const float* w2  = (const float*)d_in[6];
    const float* b2  = (const float*)d_in[7];
    const float* M1  = (const float*)d_in[8];
    const float* mb1 = (const float*)d_in[9];
    const float* M2  = (const float*)d_in[10];
    const float* mb2 = (const float*)d_in[11];
    const float* M3  = (const float*)d_in[12];
    const float* mb3 = (const float*)d_in[13];
    const int B = in_sizes[0];

    float* out_scores = (float*)d_out;
    float* out_att    = out_scores + B;
    unsigned short* w1f = (unsigned short*)d_ws;   // 64 KB frag-major bf16 W1

    prep_w1<<<128, 256, 0, stream>>>(W1, w1f);
    cdm_fwd<<<B / SPB, 256, 0, stream>>>(stu, kpi, kpl, emb, w1f, b1, w2, b2,
                                         M1, mb1, M2, mb2, M3, mb3,
                                         out_scores, out_att);
}

// Round 3
// 126.389 us; speedup vs baseline: 4.3908x; 1.5033x over previous
//
#include <hip/hip_runtime.h>
#include <hip/hip_bf16.h>

#define K_ 20
#define KD_ 128
#define HID_ 256
#define NKP_ 100
#define MS 32

using short8_t = __attribute__((ext_vector_type(8))) short;
using f32x4 = __attribute__((ext_vector_type(4))) float;

__device__ __forceinline__ unsigned short f2bf(float f) {
    union { __hip_bfloat16 h; unsigned short u; } c; c.h = __float2bfloat16(f); return c.u;
}
__device__ __forceinline__ float fast_tanh(float x) {
    return 1.f - 2.f / (__expf(2.f * x) + 1.f);
}

// W1 [128][256] f32 -> frag-major bf16: frag(n,s), lane l, elem j holds
// W1[k = s*32 + (l>>4)*8 + j][col = n*16 + (l&15)].
__global__ __launch_bounds__(256) void prep_w1(const float* __restrict__ W1,
                                               unsigned short* __restrict__ out) {
    const int i = blockIdx.x * 256 + threadIdx.x;   // 0..32767
    const int j = i & 7;
    const int l = (i >> 3) & 63;
    const int s = (i >> 9) & 3;
    const int n = i >> 11;
    const int k = s * 32 + (l >> 4) * 8 + j;
    const int col = n * 16 + (l & 15);
    out[i] = f2bf(W1[k * HID_ + col]);
}

// 8 samples/block, 2 per wave. Barrier-free: all LDS rows are wave-private.
__global__ __launch_bounds__(256, 3) void cdm_attn(
    const int* __restrict__ stu_idx, const int* __restrict__ kp_idx,
    const int* __restrict__ kp_len, const float* __restrict__ emb,
    const unsigned short* __restrict__ w1f,
    const float* __restrict__ b1, const float* __restrict__ w2,
    const float* __restrict__ b2,
    float* __restrict__ out_att, float* __restrict__ wsum_g)
{
    const int tid = threadIdx.x, lane = tid & 63, wid = tid >> 6;
    const int sA = blockIdx.x * 8 + wid * 2;

    __shared__ unsigned short vec_s[8][K_][KD_];   // 40 KB, row stride 256 B, swizzled
    __shared__ float logit_s[8][K_];
    __shared__ float att_s[8][K_];

    const int lenA = kp_len[sA], lenB = kp_len[sA + 1];

    // ---------- gather 2 samples x 20 rows -> bf16 LDS (rows >= len zeroed) ----------
    for (int h = 0; h < 2; ++h) {
        const int gs = sA + h;
        const int len = h ? lenB : lenA;
        const long long base = (long long)stu_idx[gs] * (NKP_ * KD_);
        char* smpbase = (char*)&vec_s[wid * 2 + h][0][0];
#pragma unroll
        for (int it = 0; it < 5; ++it) {
            const int r = it * 4 + (lane >> 4);
            char* dst = smpbase + r * 256 + (((lane & 15) * 16) ^ ((r & 7) << 4));
            if (r < len) {
                const int kp = kp_idx[gs * K_ + r];
                const float4* src = (const float4*)(emb + base + (long long)kp * KD_) + (lane & 15) * 2;
                const float4 v0 = src[0], v1 = src[1];
                short8_t pk;
                pk[0] = (short)f2bf(v0.x); pk[1] = (short)f2bf(v0.y);
                pk[2] = (short)f2bf(v0.z); pk[3] = (short)f2bf(v0.w);
                pk[4] = (short)f2bf(v1.x); pk[5] = (short)f2bf(v1.y);
                pk[6] = (short)f2bf(v1.z); pk[7] = (short)f2bf(v1.w);
                *(short8_t*)dst = pk;
            } else {
                const short8_t z = {0, 0, 0, 0, 0, 0, 0, 0};
                *(short8_t*)dst = z;
            }
        }
    }

    // ---------- A fragments: tile0 = A rows0-15, tile1 = B rows0-15,
    //            tile2 = leftover (A16-19 rows0-3, B16-19 rows4-7, rows8-15 pad) ----------
    short8_t A0[4], A1[4], A2[4];
    {
        const char* bA = (const char*)&vec_s[wid * 2][0][0];
        const char* bB = (const char*)&vec_s[wid * 2 + 1][0][0];
        const int rowb = (lane & 15) * 256;
        const int lr = lane & 15;
        const char* b2p = (const char*)&vec_s[wid * 2 + ((lr >> 2) & 1)][0][0] + (16 + (lr & 3)) * 256;
        const bool v2 = lr < 8;
        const short8_t z = {0, 0, 0, 0, 0, 0, 0, 0};
#pragma unroll
        for (int s = 0; s < 4; ++s) {
            const int colT = s * 64 + (lane >> 4) * 16;
            const int colA = colT ^ ((lane & 7) << 4);
            A0[s] = *(const short8_t*)(bA + rowb + colA);
            A1[s] = *(const short8_t*)(bB + rowb + colA);
            const short8_t t = *(const short8_t*)(b2p + (colT ^ ((lr & 3) << 4)));
            A2[s] = v2 ? t : z;
        }
    }

    // ---------- MFMA + fused tanh*w2 epilogue; B-frags shared by all 3 tiles ----------
    float lp0[4] = {0, 0, 0, 0}, lp1[4] = {0, 0, 0, 0}, lp2[4] = {0, 0, 0, 0};
    const int colbase = lane & 15;
    const short8_t* bfr = (const short8_t*)w1f;
#pragma unroll 4
    for (int n = 0; n < 16; ++n) {
        f32x4 a0 = {0.f, 0.f, 0.f, 0.f}, a1 = {0.f, 0.f, 0.f, 0.f}, a2 = {0.f, 0.f, 0.f, 0.f};
#pragma unroll
        for (int s = 0; s < 4; ++s) {
            const short8_t Bs = bfr[(n * 4 + s) * 64 + lane];
            a0 = __builtin_amdgcn_mfma_f32_16x16x32_bf16(A0[s], Bs, a0, 0, 0, 0);
            a1 = __builtin_amdgcn_mfma_f32_16x16x32_bf16(A1[s], Bs, a1, 0, 0, 0);
            a2 = __builtin_amdgcn_mfma_f32_16x16x32_bf16(A2[s], Bs, a2, 0, 0, 0);
        }
        const float b1v = b1[n * 16 + colbase];
        const float w2v = w2[n * 16 + colbase];
#pragma unroll
        for (int i = 0; i < 4; ++i) {
            lp0[i] += fast_tanh(a0[i] + b1v) * w2v;
            lp1[i] += fast_tanh(a1[i] + b1v) * w2v;
            lp2[i] += fast_tanh(a2[i] + b1v) * w2v;
        }
    }
#pragma unroll
    for (int i = 0; i < 4; ++i) {
#pragma unroll
        for (int m = 1; m <= 8; m <<= 1) {
            lp0[i] += __shfl_xor(lp0[i], m);
            lp1[i] += __shfl_xor(lp1[i], m);
            lp2[i] += __shfl_xor(lp2[i], m);
        }
    }
    const float b2v = b2[0];
    if ((lane & 15) == 0) {
        const int g = lane >> 4;
#pragma unroll
        for (int i = 0; i < 4; ++i) {
            logit_s[wid * 2][g * 4 + i]     = lp0[i] + b2v;
            logit_s[wid * 2 + 1][g * 4 + i] = lp1[i] + b2v;
        }
        if (g < 2) {
#pragma unroll
            for (int i = 0; i < 4; ++i) logit_s[wid * 2 + g][16 + i] = lp2[i] + b2v;
        }
    }

    // ---------- softmax: half-wave per sample ----------
    {
        const int j = lane & 31;
        const int hh = lane >> 5;
        const int smp = wid * 2 + hh;
        const int gsS = sA + hh;
        const int lenS = hh ? lenB : lenA;
        const float lgv = (j < K_) ? logit_s[smp][j] : -1e30f;
        float mx = lgv;
#pragma unroll
        for (int m = 16; m >= 1; m >>= 1) mx = fmaxf(mx, __shfl_xor(mx, m, 32));
        const float e = (j < K_) ? __expf(lgv - mx) : 0.f;
        float ssum = e;
#pragma unroll
        for (int m = 16; m >= 1; m >>= 1) ssum += __shfl_xor(ssum, m, 32);
        const float a = (j < lenS) ? e / ssum : 0.f;
        if (j < K_) { att_s[smp][j] = a; out_att[gsS * K_ + j] = a; }
    }

    // ---------- weighted sum -> global wsum ----------
    for (int h = 0; h < 2; ++h) {
        const int smp = wid * 2 + h;
        const int gs = sA + h;
        const int len = h ? lenB : lenA;
        const char* vb = (const char*)&vec_s[smp][0][0];
        float s0 = 0.f, s1 = 0.f;
        for (int k = 0; k < len; ++k) {
            const unsigned int u = *(const unsigned int*)(vb + k * 256 + ((lane * 4) ^ ((k & 7) << 4)));
            const float av = att_s[smp][k];
            s0 = fmaf(av, __uint_as_float(u << 16), s0);
            s1 = fmaf(av, __uint_as_float(u & 0xffff0000u), s1);
        }
        *(float2*)(wsum_g + (long long)gs * KD_ + lane * 2) = make_float2(s0, s1);
    }
}

// MLP tail: 32 samples/block (8 per wave, wave-private, barrier-free).
__global__ __launch_bounds__(256, 2) void cdm_mlp(
    const float* __restrict__ wsum_g,
    const float* __restrict__ M1, const float* __restrict__ mb1,
    const float* __restrict__ M2, const float* __restrict__ mb2,
    const float* __restrict__ M3, const float* __restrict__ mb3,
    float* __restrict__ out_scores)
{
    const int tid = threadIdx.x, lane = tid & 63, wid = tid >> 6;
    const int s0 = blockIdx.x * MS;
    const int sb = wid * 8;

    __shared__ float ws_s[MS][132];   // padded strides: conflict-free b128 broadcasts
    __shared__ float h1_s[MS][260];
    __shared__ float h2_s[MS][132];

    // wave-local wsum load (coalesced)
#pragma unroll
    for (int e = 0; e < 16; ++e) {
        const int idx = e * 64 + lane;           // 0..1023
        const int sl = idx >> 7, d = idx & 127;
        ws_s[sb + sl][d] = wsum_g[(long long)(s0 + sb + sl) * KD_ + d];
    }

    // ---- h1 = relu(ws @ M1 + mb1): lane owns 4 cols x 8 samples ----
    {
        const int c0 = lane * 4;
        const float4 bias = *(const float4*)&mb1[c0];
        f32x4 acc[8];
#pragma unroll
        for (int si = 0; si < 8; ++si) { acc[si][0] = bias.x; acc[si][1] = bias.y; acc[si][2] = bias.z; acc[si][3] = bias.w; }
        for (int d = 0; d < KD_; d += 4) {
            float4 wv[8];
#pragma unroll
            for (int si = 0; si < 8; ++si) wv[si] = *(const float4*)&ws_s[sb + si][d];
#pragma unroll
            for (int dd = 0; dd < 4; ++dd) {
                const float4 mv = *(const float4*)&M1[(d + dd) * HID_ + c0];
#pragma unroll
                for (int si = 0; si < 8; ++si) {
                    const float w = ((const float*)&wv[si])[dd];
                    acc[si][0] = fmaf(w, mv.x, acc[si][0]);
                    acc[si][1] = fmaf(w, mv.y, acc[si][1]);
                    acc[si][2] = fmaf(w, mv.z, acc[si][2]);
                    acc[si][3] = fmaf(w, mv.w, acc[si][3]);
                }
            }
        }
#pragma unroll
        for (int si = 0; si < 8; ++si) {
            float4 r;
            r.x = fmaxf(acc[si][0], 0.f); r.y = fmaxf(acc[si][1], 0.f);
            r.z = fmaxf(acc[si][2], 0.f); r.w = fmaxf(acc[si][3], 0.f);
            *(float4*)&h1_s[sb + si][c0] = r;
        }
    }

    // ---- h2 = relu(h1 @ M2 + mb2): lane owns 2 cols x 8 samples ----
    {
        const int c2 = lane * 2;
        float a0[8], a1[8];
        const float2 bias = *(const float2*)&mb2[c2];
#pragma unroll
        for (int si = 0; si < 8; ++si) { a0[si] = bias.x; a1[si] = bias.y; }
        for (int k = 0; k < HID_; k += 4) {
            float4 hv[8];
#pragma unroll
            for (int si = 0; si < 8; ++si) hv[si] = *(const float4*)&h1_s[sb + si][k];
#pragma unroll
            for (int kk = 0; kk < 4; ++kk) {
                const float2 m2v = *(const float2*)&M2[(k + kk) * (HID_ / 2) + c2];
#pragma unroll
                for (int si = 0; si < 8; ++si) {
                    const float hvv = ((const float*)&hv[si])[kk];
                    a0[si] = fmaf(hvv, m2v.x, a0[si]);
                    a1[si] = fmaf(hvv, m2v.y, a1[si]);
                }
            }
        }
#pragma unroll
        for (int si = 0; si < 8; ++si) {
            h2_s[sb + si][c2]     = fmaxf(a0[si], 0.f);
            h2_s[sb + si][c2 + 1] = fmaxf(a1[si], 0.f);
        }
    }

    // ---- score = sigmoid(h2 @ M3 + mb3): 8 lanes per sample ----
    {
        const int sl = lane >> 3, e = lane & 7;
        const int smp = sb + sl;
        float p = 0.f;
#pragma unroll
        for (int d = e; d < KD_; d += 8) p = fmaf(h2_s[smp][d], M3[d], p);
        p += __shfl_xor(p, 1); p += __shfl_xor(p, 2); p += __shfl_xor(p, 4);
        if (e == 0) out_scores[s0 + smp] = 1.f / (1.f + __expf(-(p + mb3[0])));
    }
}

extern "C" void kernel_launch(void* const* d_in, const int* in_sizes, int n_in,
                              void* d_out, int out_size, void* d_ws, size_t ws_size,
                              hipStream_t stream) {
    const int*   stu = (const int*)d_in[0];
    const int*   kpi = (const int*)d_in[1];
    const int*   kpl = (const int*)d_in[2];
    const float* emb = (const float*)d_in[3];
    const float* W1  = (const float*)d_in[4];
    const float* b1  = (const float*)d_in[5];
    const float* w2  = (const float*)d_in[6];
    const float* b2  = (const float*)d_in[7];
    const float* M1  = (const float*)d_in[8];
    const float* mb1 = (const float*)d_in[9];
    const float* M2  = (const float*)d_in[10];
    const float* mb2 = (const float*)d_in[11];
    const float* M3  = (const float*)d_in[12];
    const float* mb3 = (const float*)d_in[13];
    const int B = in_sizes[0];

    float* out_scores = (float*)d_out;
    float* out_att    = out_scores + B;

    unsigned short* w1f = (unsigned short*)d_ws;                 // 64 KB
    float* wsum_g = (float*)((char*)d_ws + 65536);               // B*128 f32 = 8 MB

    prep_w1<<<128, 256, 0, stream>>>(W1, w1f);
    cdm_attn<<<B / 8, 256, 0, stream>>>(stu, kpi, kpl, emb, w1f, b1, w2, b2,
                                        out_att, wsum_g);
    cdm_mlp<<<B / MS, 256, 0, stream>>>(wsum_g, M1, mb1, M2, mb2, M3, mb3, out_scores);
}

// Round 4
// 110.370 us; speedup vs baseline: 5.0281x; 1.1451x over previous
//
#include <hip/hip_runtime.h>
#include <hip/hip_bf16.h>

#define K_ 20
#define KD_ 128
#define HID_ 256
#define NKP_ 100

using short8_t = __attribute__((ext_vector_type(8))) short;
using f32x4 = __attribute__((ext_vector_type(4))) float;

__device__ __forceinline__ unsigned short f2bf(float f) {
    union { __hip_bfloat16 h; unsigned short u; } c; c.h = __float2bfloat16(f); return c.u;
}
__device__ __forceinline__ float vexp(float x) { float r; asm("v_exp_f32 %0, %1" : "=v"(r) : "v"(x)); return r; }
__device__ __forceinline__ float vrcp(float x) { float r; asm("v_rcp_f32 %0, %1" : "=v"(r) : "v"(x)); return r; }

#define CEXP 2.885390081777927f   /* 2*log2(e) */

// src [KR][NC] f32 -> frag-major bf16 (MFMA 16x16x32 B-operand layout):
// frag f = n*(KR/32)+s, lane l, elem j = src[s*32+(l>>4)*8+j][n*16+(l&15)]
__global__ __launch_bounds__(256) void prep_frags(
    const float* __restrict__ W1, const float* __restrict__ M1,
    const float* __restrict__ M2, unsigned short* __restrict__ w1f,
    unsigned short* __restrict__ m1f, unsigned short* __restrict__ m2f)
{
    const int b = blockIdx.x;
    const float* src; unsigned short* dst; int nc, smask, nshift, ib;
    if (b < 128)      { src = W1; dst = w1f; nc = 256; smask = 3; nshift = 2; ib = b; }
    else if (b < 256) { src = M1; dst = m1f; nc = 256; smask = 3; nshift = 2; ib = b - 128; }
    else              { src = M2; dst = m2f; nc = 128; smask = 7; nshift = 3; ib = b - 256; }
    const int i = ib * 256 + threadIdx.x;
    const int j = i & 7, l = (i >> 3) & 63, f = i >> 9;
    const int s = f & smask, n = f >> nshift;
    const int k = s * 32 + (l >> 4) * 8 + j;
    const int col = n * 16 + (l & 15);
    dst[i] = f2bf(src[k * nc + col]);
}

// 8 samples/block, 4 waves. Wave w owns hidden cols [64w,64w+64) (B-frags in
// registers, loaded once). 4 passes of 2 samples; cross-wave logit reduce in LDS.
__global__ __launch_bounds__(256, 3) void cdm_attn(
    const int* __restrict__ stu_idx, const int* __restrict__ kp_idx,
    const int* __restrict__ kp_len, const float* __restrict__ emb,
    const unsigned short* __restrict__ w1f,
    const float* __restrict__ b1, const float* __restrict__ w2,
    const float* __restrict__ b2,
    float* __restrict__ out_att, unsigned short* __restrict__ wsum_g)
{
    const int tid = threadIdx.x, lane = tid & 63, w = tid >> 6;
    const int base = blockIdx.x * 8;

    __shared__ unsigned short vec_s[8][K_][KD_];   // 40 KB, 256B row stride, swizzled
    __shared__ float lp_s[2][2][4][24];            // [parity][sample][wave][row]

    // ---- B-fragments (wave-owned n-slice), loaded once ----
    short8_t Bf[4][4];
    {
        const short8_t* bfr = (const short8_t*)w1f;
#pragma unroll
        for (int nn = 0; nn < 4; ++nn)
#pragma unroll
            for (int s = 0; s < 4; ++s)
                Bf[nn][s] = bfr[((w * 4 + nn) * 4 + s) * 64 + lane];
    }

    // ---- per-wave epilogue constants ----
    float b1C[4], w2r[4], n2r[4];
#pragma unroll
    for (int nn = 0; nn < 4; ++nn) {
        const int c = (w * 4 + nn) * 16 + (lane & 15);
        b1C[nn] = b1[c] * CEXP;
        w2r[nn] = w2[c];
        n2r[nn] = -2.f * w2r[nn];
    }
    const float b2v = b2[0];

    // ---- gather: wave w stages samples 2w,2w+1 (branch-free, batched loads) ----
    for (int h = 0; h < 2; ++h) {
        const int gs = base + 2 * w + h;
        const int len = kp_len[gs];
        const long long eb = (long long)stu_idx[gs] * (NKP_ * KD_);
        const int g = lane >> 4, c16 = lane & 15;
        float4 va[5], vb[5];
#pragma unroll
        for (int it = 0; it < 5; ++it) {
            const int r = it * 4 + g;
            const int kp = kp_idx[gs * K_ + r];              // always in-bounds
            const float4* src = (const float4*)(emb + eb + (long long)kp * KD_) + c16 * 2;
            va[it] = src[0]; vb[it] = src[1];
        }
        char* sb = (char*)&vec_s[2 * w + h][0][0];
#pragma unroll
        for (int it = 0; it < 5; ++it) {
            const int r = it * 4 + g;
            const bool vm = r < len;
            short8_t pk;
            pk[0] = (short)f2bf(va[it].x); pk[1] = (short)f2bf(va[it].y);
            pk[2] = (short)f2bf(va[it].z); pk[3] = (short)f2bf(va[it].w);
            pk[4] = (short)f2bf(vb[it].x); pk[5] = (short)f2bf(vb[it].y);
            pk[6] = (short)f2bf(vb[it].z); pk[7] = (short)f2bf(vb[it].w);
            const short8_t z = {0, 0, 0, 0, 0, 0, 0, 0};
            pk = vm ? pk : z;
            *(short8_t*)(sb + r * 256 + ((c16 * 16) ^ ((r & 7) << 4))) = pk;
        }
    }
    __syncthreads();

    // ---- 4 passes of 2 samples ----
    for (int p = 0; p < 4; ++p) {
        const int sp = 2 * p;
        // A-frags: tile0 = s0 rows0-15, tile1 = s1 rows0-15,
        // tile2 = [s0 r16-19 | s1 r16-19 | pad]
        short8_t A0[4], A1[4], A2[4];
        {
            const char* bA = (const char*)&vec_s[sp][0][0];
            const char* bB = (const char*)&vec_s[sp + 1][0][0];
            const int lr = lane & 15;
            const int rowb = lr * 256;
            const char* t2b = (const char*)&vec_s[sp + ((lr >> 2) & 1)][0][0] + (16 + (lr & 3)) * 256;
            const bool v2 = lr < 8;
            const short8_t z = {0, 0, 0, 0, 0, 0, 0, 0};
#pragma unroll
            for (int s = 0; s < 4; ++s) {
                const int colT = s * 64 + (lane >> 4) * 16;
                const int colA = colT ^ ((lr & 7) << 4);
                A0[s] = *(const short8_t*)(bA + rowb + colA);
                A1[s] = *(const short8_t*)(bB + rowb + colA);
                const short8_t t = *(const short8_t*)(t2b + (colT ^ ((lr & 3) << 4)));
                A2[s] = v2 ? t : z;
            }
        }

        float lp0[4] = {0, 0, 0, 0}, lp1[4] = {0, 0, 0, 0}, lp2[4] = {0, 0, 0, 0};
#pragma unroll
        for (int nn = 0; nn < 4; ++nn) {
            f32x4 a0 = {0.f, 0.f, 0.f, 0.f}, a1 = {0.f, 0.f, 0.f, 0.f}, a2 = {0.f, 0.f, 0.f, 0.f};
#pragma unroll
            for (int s = 0; s < 4; ++s) {
                a0 = __builtin_amdgcn_mfma_f32_16x16x32_bf16(A0[s], Bf[nn][s], a0, 0, 0, 0);
                a1 = __builtin_amdgcn_mfma_f32_16x16x32_bf16(A1[s], Bf[nn][s], a1, 0, 0, 0);
                a2 = __builtin_amdgcn_mfma_f32_16x16x32_bf16(A2[s], Bf[nn][s], a2, 0, 0, 0);
            }
            const float bc = b1C[nn], wv = w2r[nn], n2 = n2r[nn];
#pragma unroll
            for (int i = 0; i < 4; ++i) {
                lp0[i] = fmaf(n2, vrcp(vexp(fmaf(a0[i], CEXP, bc)) + 1.f), lp0[i] + wv);
                lp1[i] = fmaf(n2, vrcp(vexp(fmaf(a1[i], CEXP, bc)) + 1.f), lp1[i] + wv);
                lp2[i] = fmaf(n2, vrcp(vexp(fmaf(a2[i], CEXP, bc)) + 1.f), lp2[i] + wv);
            }
        }
#pragma unroll
        for (int i = 0; i < 4; ++i) {
#pragma unroll
            for (int m = 1; m <= 8; m <<= 1) {
                lp0[i] += __shfl_xor(lp0[i], m);
                lp1[i] += __shfl_xor(lp1[i], m);
                lp2[i] += __shfl_xor(lp2[i], m);
            }
        }
        const int par = p & 1;
        if ((lane & 15) == 0) {
            const int g = lane >> 4;
#pragma unroll
            for (int i = 0; i < 4; ++i) {
                lp_s[par][0][w][g * 4 + i] = lp0[i];
                lp_s[par][1][w][g * 4 + i] = lp1[i];
            }
            if (g < 2) {
#pragma unroll
                for (int i = 0; i < 4; ++i) lp_s[par][g][w][16 + i] = lp2[i];
            }
        }
        __syncthreads();

        // softmax (computed redundantly by every wave; half-wave per sample)
        const int j = lane & 31, hh = lane >> 5;
        const int gsS = base + sp + hh;
        const int lenS = kp_len[gsS];
        float logit = -1e30f;
        if (j < K_) logit = b2v + lp_s[par][hh][0][j] + lp_s[par][hh][1][j]
                                + lp_s[par][hh][2][j] + lp_s[par][hh][3][j];
        float mx = logit;
#pragma unroll
        for (int m = 16; m >= 1; m >>= 1) mx = fmaxf(mx, __shfl_xor(mx, m, 32));
        const float e = (j < K_) ? vexp((logit - mx) * 1.44269504f) : 0.f;
        float sm = e;
#pragma unroll
        for (int m = 16; m >= 1; m >>= 1) sm += __shfl_xor(sm, m, 32);
        const float attv = (j < lenS) ? e * vrcp(sm) : 0.f;
        if (w == 0 && j < K_) out_att[gsS * K_ + j] = attv;

        // weighted sum: wave w covers dims [32w,32w+32) for both samples
        const int d = w * 32 + (lane & 31);
        const char* vb2 = (const char*)&vec_s[sp + hh][0][0];
        const int lm = max(lenS, __shfl_xor(lenS, 32));
        float sacc = 0.f;
        for (int k = 0; k < lm; ++k) {
            const unsigned short u = *(const unsigned short*)(vb2 + k * 256 + ((2 * d) ^ ((k & 7) << 4)));
            const float av = __shfl(attv, k + (lane & 32));
            sacc = fmaf(av, __uint_as_float(((unsigned)u) << 16), sacc);
        }
        wsum_g[gsS * KD_ + d] = f2bf(sacc);
    }
}

// MLP tail on MFMA: 32 samples/block, n-split B-frags in registers.
__global__ __launch_bounds__(256, 3) void cdm_mlp(
    const unsigned short* __restrict__ wsum_g,
    const unsigned short* __restrict__ m1f, const unsigned short* __restrict__ m2f,
    const float* __restrict__ mb1, const float* __restrict__ mb2,
    const float* __restrict__ M3, const float* __restrict__ mb3,
    float* __restrict__ out_scores)
{
    const int tid = threadIdx.x, lane = tid & 63, w = tid >> 6;
    const int S0 = blockIdx.x * 32;

    __shared__ unsigned short h1_s[32][HID_];  // 16 KB, 512B row stride, swizzled
    __shared__ float sc_s[4][32];

    // ---- pass 1: h1 = relu(ws @ M1 + mb1) ----
    short8_t Aw[2][4];
#pragma unroll
    for (int m = 0; m < 2; ++m)
#pragma unroll
        for (int s = 0; s < 4; ++s)
            Aw[m][s] = *(const short8_t*)(wsum_g + (S0 + m * 16 + (lane & 15)) * KD_
                                          + s * 32 + (lane >> 4) * 8);
    short8_t B1r[4][4];
    {
        const short8_t* bf1 = (const short8_t*)m1f;
#pragma unroll
        for (int nn = 0; nn < 4; ++nn)
#pragma unroll
            for (int s = 0; s < 4; ++s)
                B1r[nn][s] = bf1[((w * 4 + nn) * 4 + s) * 64 + lane];
    }
#pragma unroll
    for (int nn = 0; nn < 4; ++nn) {
        f32x4 c0 = {0.f, 0.f, 0.f, 0.f}, c1 = {0.f, 0.f, 0.f, 0.f};
#pragma unroll
        for (int s = 0; s < 4; ++s) {
            c0 = __builtin_amdgcn_mfma_f32_16x16x32_bf16(Aw[0][s], B1r[nn][s], c0, 0, 0, 0);
            c1 = __builtin_amdgcn_mfma_f32_16x16x32_bf16(Aw[1][s], B1r[nn][s], c1, 0, 0, 0);
        }
        const int col = (w * 4 + nn) * 16 + (lane & 15);
        const float bias = mb1[col];
#pragma unroll
        for (int i = 0; i < 4; ++i) {
            const int r0 = (lane >> 4) * 4 + i;
            const int r1 = 16 + r0;
            *(unsigned short*)((char*)h1_s + r0 * 512 + ((2 * col) ^ ((r0 & 7) << 4)))
                = f2bf(fmaxf(c0[i] + bias, 0.f));
            *(unsigned short*)((char*)h1_s + r1 * 512 + ((2 * col) ^ ((r0 & 7) << 4)))
                = f2bf(fmaxf(c1[i] + bias, 0.f));
        }
    }
    __syncthreads();

    // ---- pass 2: h2 = relu(h1 @ M2 + mb2), fused M3 dot ----
    short8_t B2r[2][8];
    {
        const short8_t* bf2 = (const short8_t*)m2f;
#pragma unroll
        for (int nn = 0; nn < 2; ++nn)
#pragma unroll
            for (int s = 0; s < 8; ++s)
                B2r[nn][s] = bf2[((w * 2 + nn) * 8 + s) * 64 + lane];
    }
    f32x4 d00 = {0.f, 0.f, 0.f, 0.f}, d01 = {0.f, 0.f, 0.f, 0.f};
    f32x4 d10 = {0.f, 0.f, 0.f, 0.f}, d11 = {0.f, 0.f, 0.f, 0.f};
    {
        const int lr = lane & 15;
#pragma unroll
        for (int s = 0; s < 8; ++s) {
            const int off = (s * 64 + (lane >> 4) * 16) ^ ((lr & 7) << 4);
            const short8_t Ah0 = *(const short8_t*)((const char*)h1_s + lr * 512 + off);
            const short8_t Ah1 = *(const short8_t*)((const char*)h1_s + (16 + lr) * 512 + off);
            d00 = __builtin_amdgcn_mfma_f32_16x16x32_bf16(Ah0, B2r[0][s], d00, 0, 0, 0);
            d01 = __builtin_amdgcn_mfma_f32_16x16x32_bf16(Ah0, B2r[1][s], d01, 0, 0, 0);
            d10 = __builtin_amdgcn_mfma_f32_16x16x32_bf16(Ah1, B2r[0][s], d10, 0, 0, 0);
            d11 = __builtin_amdgcn_mfma_f32_16x16x32_bf16(Ah1, B2r[1][s], d11, 0, 0, 0);
        }
    }
    float part0[4] = {0, 0, 0, 0}, part1[4] = {0, 0, 0, 0};
#pragma unroll
    for (int nn = 0; nn < 2; ++nn) {
        const int col = (w * 2 + nn) * 16 + (lane & 15);
        const float bb = mb2[col], m3v = M3[col];
        const f32x4 dm0 = nn ? d01 : d00;
        const f32x4 dm1 = nn ? d11 : d10;
#pragma unroll
        for (int i = 0; i < 4; ++i) {
            part0[i] = fmaf(fmaxf(dm0[i] + bb, 0.f), m3v, part0[i]);
            part1[i] = fmaf(fmaxf(dm1[i] + bb, 0.f), m3v, part1[i]);
        }
    }
#pragma unroll
    for (int i = 0; i < 4; ++i) {
#pragma unroll
        for (int m = 1; m <= 8; m <<= 1) {
            part0[i] += __shfl_xor(part0[i], m);
            part1[i] += __shfl_xor(part1[i], m);
        }
    }
    if ((lane & 15) == 0) {
        const int g = lane >> 4;
#pragma unroll
        for (int i = 0; i < 4; ++i) {
            sc_s[w][g * 4 + i] = part0[i];
            sc_s[w][16 + g * 4 + i] = part1[i];
        }
    }
    __syncthreads();
    if (tid < 32) {
        const float sc = sc_s[0][tid] + sc_s[1][tid] + sc_s[2][tid] + sc_s[3][tid] + mb3[0];
        out_scores[S0 + tid] = 1.f / (1.f + __expf(-sc));
    }
}

extern "C" void kernel_launch(void* const* d_in, const int* in_sizes, int n_in,
                              void* d_out, int out_size, void* d_ws, size_t ws_size,
                              hipStream_t stream) {
    const int*   stu = (const int*)d_in[0];
    const int*   kpi = (const int*)d_in[1];
    const int*   kpl = (const int*)d_in[2];
    const float* emb = (const float*)d_in[3];
    const float* W1  = (const float*)d_in[4];
    const float* b1  = (const float*)d_in[5];
    const float* w2  = (const float*)d_in[6];
    const float* b2  = (const float*)d_in[7];
    const float* M1  = (const float*)d_in[8];
    const float* mb1 = (const float*)d_in[9];
    const float* M2  = (const float*)d_in[10];
    const float* mb2 = (const float*)d_in[11];
    const float* M3  = (const float*)d_in[12];
    const float* mb3 = (const float*)d_in[13];
    const int B = in_sizes[0];

    float* out_scores = (float*)d_out;
    float* out_att    = out_scores + B;

    unsigned short* w1f  = (unsigned short*)d_ws;       // 64 KB
    unsigned short* m1f  = w1f + 32768;                 // 64 KB
    unsigned short* m2f  = m1f + 32768;                 // 64 KB
    unsigned short* wsum = m2f + 32768;                 // B*128 bf16 = 4 MB

    prep_frags<<<384, 256, 0, stream>>>(W1, M1, M2, w1f, m1f, m2f);
    cdm_attn<<<B / 8, 256, 0, stream>>>(stu, kpi, kpl, emb, w1f, b1, w2, b2,
                                        out_att, wsum);
    cdm_mlp<<<B / 32, 256, 0, stream>>>(wsum, m1f, m2f, mb1, mb2, M3, mb3, out_scores);
}

// Round 5
// 88.945 us; speedup vs baseline: 6.2392x; 1.2409x over previous
//
#include <hip/hip_runtime.h>
#include <hip/hip_bf16.h>

#define K_ 20
#define KD_ 128
#define HID_ 256
#define NKP_ 100

using short8_t = __attribute__((ext_vector_type(8))) short;
using f32x4 = __attribute__((ext_vector_type(4))) float;

__device__ __forceinline__ unsigned short f2bf(float f) {
    union { __hip_bfloat16 h; unsigned short u; } c; c.h = __float2bfloat16(f); return c.u;
}
__device__ __forceinline__ float vexp(float x) { float r; asm("v_exp_f32 %0, %1" : "=v"(r) : "v"(x)); return r; }
__device__ __forceinline__ float vrcp(float x) { float r; asm("v_rcp_f32 %0, %1" : "=v"(r) : "v"(x)); return r; }

#define CEXP 2.885390081777927f   /* 2*log2(e) */

// src [KR][NC] f32 -> frag-major bf16 (MFMA 16x16x32 B-operand layout):
// frag f = n*(KR/32)+s, lane l, elem j = src[s*32+(l>>4)*8+j][n*16+(l&15)]
__global__ __launch_bounds__(256) void prep_frags(
    const float* __restrict__ W1, const float* __restrict__ M1,
    const float* __restrict__ M2, unsigned short* __restrict__ w1f,
    unsigned short* __restrict__ m1f, unsigned short* __restrict__ m2f)
{
    const int b = blockIdx.x;
    const float* src; unsigned short* dst; int nc, smask, nshift, ib;
    if (b < 128)      { src = W1; dst = w1f; nc = 256; smask = 3; nshift = 2; ib = b; }
    else if (b < 256) { src = M1; dst = m1f; nc = 256; smask = 3; nshift = 2; ib = b - 128; }
    else              { src = M2; dst = m2f; nc = 128; smask = 7; nshift = 3; ib = b - 256; }
    const int i = ib * 256 + threadIdx.x;
    const int j = i & 7, l = (i >> 3) & 63, f = i >> 9;
    const int s = f & smask, n = f >> nshift;
    const int k = s * 32 + (l >> 4) * 8 + j;
    const int col = n * 16 + (l & 15);
    dst[i] = f2bf(src[k * nc + col]);
}

// 8 samples/block, 4 waves. Wave w owns hidden cols [64w,64w+64) (B-frags in
// registers). 4 passes of 2 samples; cross-wave logit reduce in LDS.
// Masked rows use the precomputed constant logit0 (zero-vec logit).
__global__ __launch_bounds__(256, 3) void cdm_attn(
    const int* __restrict__ stu_idx, const int* __restrict__ kp_idx,
    const int* __restrict__ kp_len, const float* __restrict__ emb,
    const unsigned short* __restrict__ w1f,
    const float* __restrict__ b1, const float* __restrict__ w2,
    const float* __restrict__ b2,
    float* __restrict__ out_att, unsigned short* __restrict__ wsum_g)
{
    const int tid = threadIdx.x, lane = tid & 63, w = tid >> 6;
    const int base = blockIdx.x * 8;

    __shared__ unsigned short vec_s[8][K_][KD_];   // 40 KB, 256B row stride, swizzled
    __shared__ float lp_s[2][2][4][24];            // [parity][sample][wave][row]
    __shared__ float l0_s[4];                      // per-wave logit0 partials

    // ---- B-fragments (wave-owned n-slice), loaded once ----
    short8_t Bf[4][4];
    {
        const short8_t* bfr = (const short8_t*)w1f;
#pragma unroll
        for (int nn = 0; nn < 4; ++nn)
#pragma unroll
            for (int s = 0; s < 4; ++s)
                Bf[nn][s] = bfr[((w * 4 + nn) * 4 + s) * 64 + lane];
    }

    // ---- per-wave epilogue constants ----
    float b1C[4], w2r[4], n2r[4];
#pragma unroll
    for (int nn = 0; nn < 4; ++nn) {
        const int c = (w * 4 + nn) * 16 + (lane & 15);
        b1C[nn] = b1[c] * CEXP;
        w2r[nn] = w2[c];
        n2r[nn] = -2.f * w2r[nn];
    }
    const float b2v = b2[0];

    // ---- gather: wave w stages samples 2w,2w+1 (predicated: only rows < len) ----
    for (int h = 0; h < 2; ++h) {
        const int gs = base + 2 * w + h;
        const int len = kp_len[gs];
        const long long eb = (long long)stu_idx[gs] * (NKP_ * KD_);
        const int g = lane >> 4, c16 = lane & 15;
        float4 va[5], vb[5];
#pragma unroll
        for (int it = 0; it < 5; ++it) {
            va[it] = make_float4(0.f, 0.f, 0.f, 0.f);
            vb[it] = make_float4(0.f, 0.f, 0.f, 0.f);
            const int r = it * 4 + g;
            if (r < len) {
                const int kp = kp_idx[gs * K_ + r];
                const float4* src = (const float4*)(emb + eb + (long long)kp * KD_) + c16 * 2;
                va[it] = src[0]; vb[it] = src[1];
            }
        }
        char* sb = (char*)&vec_s[2 * w + h][0][0];
#pragma unroll
        for (int it = 0; it < 5; ++it) {
            const int r = it * 4 + g;
            short8_t pk;
            pk[0] = (short)f2bf(va[it].x); pk[1] = (short)f2bf(va[it].y);
            pk[2] = (short)f2bf(va[it].z); pk[3] = (short)f2bf(va[it].w);
            pk[4] = (short)f2bf(vb[it].x); pk[5] = (short)f2bf(vb[it].y);
            pk[6] = (short)f2bf(vb[it].z); pk[7] = (short)f2bf(vb[it].w);
            *(short8_t*)(sb + r * 256 + ((c16 * 16) ^ ((r & 7) << 4))) = pk;
        }
    }

    // ---- logit0 partial for this wave's 64 cols: sum tanh(b1)*w2 ----
    {
        float p = 0.f;
#pragma unroll
        for (int nn = 0; nn < 4; ++nn)
            p = fmaf(n2r[nn], vrcp(vexp(b1C[nn]) + 1.f), p + w2r[nn]);
#pragma unroll
        for (int m = 1; m <= 8; m <<= 1) p += __shfl_xor(p, m);
        if (lane == 0) l0_s[w] = p;
    }
    __syncthreads();
    const float logit0 = l0_s[0] + l0_s[1] + l0_s[2] + l0_s[3] + b2v;

    // ---- 4 passes of 2 samples ----
    for (int p = 0; p < 4; ++p) {
        const int sp = 2 * p;
        const int lA = kp_len[base + sp], lB = kp_len[base + sp + 1];
        const bool need2 = (lA > 16) || (lB > 16);   // block-uniform

        // A-frags: tile0 = s0 rows0-15, tile1 = s1 rows0-15
        short8_t A0[4], A1[4];
        {
            const char* bA = (const char*)&vec_s[sp][0][0];
            const char* bB = (const char*)&vec_s[sp + 1][0][0];
            const int lr = lane & 15;
            const int rowb = lr * 256;
#pragma unroll
            for (int s = 0; s < 4; ++s) {
                const int colA = (s * 64 + (lane >> 4) * 16) ^ ((lr & 7) << 4);
                A0[s] = *(const short8_t*)(bA + rowb + colA);
                A1[s] = *(const short8_t*)(bB + rowb + colA);
            }
        }

        float lp0[4] = {0, 0, 0, 0}, lp1[4] = {0, 0, 0, 0};
#pragma unroll
        for (int nn = 0; nn < 4; ++nn) {
            f32x4 a0 = {0.f, 0.f, 0.f, 0.f}, a1 = {0.f, 0.f, 0.f, 0.f};
#pragma unroll
            for (int s = 0; s < 4; ++s) {
                a0 = __builtin_amdgcn_mfma_f32_16x16x32_bf16(A0[s], Bf[nn][s], a0, 0, 0, 0);
                a1 = __builtin_amdgcn_mfma_f32_16x16x32_bf16(A1[s], Bf[nn][s], a1, 0, 0, 0);
            }
            const float bc = b1C[nn], wv = w2r[nn], n2 = n2r[nn];
#pragma unroll
            for (int i = 0; i < 4; ++i) {
                lp0[i] = fmaf(n2, vrcp(vexp(fmaf(a0[i], CEXP, bc)) + 1.f), lp0[i] + wv);
                lp1[i] = fmaf(n2, vrcp(vexp(fmaf(a1[i], CEXP, bc)) + 1.f), lp1[i] + wv);
            }
        }
#pragma unroll
        for (int i = 0; i < 4; ++i) {
#pragma unroll
            for (int m = 1; m <= 8; m <<= 1) {
                lp0[i] += __shfl_xor(lp0[i], m);
                lp1[i] += __shfl_xor(lp1[i], m);
            }
        }
        const int par = p & 1;
        if ((lane & 15) == 0) {
            const int g = lane >> 4;
#pragma unroll
            for (int i = 0; i < 4; ++i) {
                lp_s[par][0][w][g * 4 + i] = lp0[i];
                lp_s[par][1][w][g * 4 + i] = lp1[i];
            }
        }

        // tile2 (rows 16-19 of both samples) only when some len > 16
        if (need2) {
            short8_t A2[4];
            const int lr = lane & 15;
            const char* t2b = (const char*)&vec_s[sp + ((lr >> 2) & 1)][0][0] + (16 + (lr & 3)) * 256;
            const bool v2 = lr < 8;
            const short8_t z = {0, 0, 0, 0, 0, 0, 0, 0};
#pragma unroll
            for (int s = 0; s < 4; ++s) {
                const int colT = s * 64 + (lane >> 4) * 16;
                const short8_t t = *(const short8_t*)(t2b + (colT ^ ((lr & 3) << 4)));
                A2[s] = v2 ? t : z;
            }
            float lp2[4] = {0, 0, 0, 0};
#pragma unroll
            for (int nn = 0; nn < 4; ++nn) {
                f32x4 a2 = {0.f, 0.f, 0.f, 0.f};
#pragma unroll
                for (int s = 0; s < 4; ++s)
                    a2 = __builtin_amdgcn_mfma_f32_16x16x32_bf16(A2[s], Bf[nn][s], a2, 0, 0, 0);
                const float bc = b1C[nn], wv = w2r[nn], n2 = n2r[nn];
#pragma unroll
                for (int i = 0; i < 4; ++i)
                    lp2[i] = fmaf(n2, vrcp(vexp(fmaf(a2[i], CEXP, bc)) + 1.f), lp2[i] + wv);
            }
#pragma unroll
            for (int i = 0; i < 4; ++i) {
#pragma unroll
                for (int m = 1; m <= 8; m <<= 1) lp2[i] += __shfl_xor(lp2[i], m);
            }
            if ((lane & 15) == 0 && (lane >> 4) < 2) {
                const int g = lane >> 4;
#pragma unroll
                for (int i = 0; i < 4; ++i) lp_s[par][g][w][16 + i] = lp2[i];
            }
        }
        __syncthreads();

        // softmax (redundant per wave; half-wave per sample)
        const int j = lane & 31, hh = lane >> 5;
        const int gsS = base + sp + hh;
        const int lenS = hh ? lB : lA;
        float logit = -1e30f;
        if (j < K_) {
            logit = (j < lenS)
                ? b2v + lp_s[par][hh][0][j] + lp_s[par][hh][1][j]
                      + lp_s[par][hh][2][j] + lp_s[par][hh][3][j]
                : logit0;
        }
        float mx = logit;
#pragma unroll
        for (int m = 16; m >= 1; m >>= 1) mx = fmaxf(mx, __shfl_xor(mx, m, 32));
        const float e = (j < K_) ? vexp((logit - mx) * 1.44269504f) : 0.f;
        float sm = e;
#pragma unroll
        for (int m = 16; m >= 1; m >>= 1) sm += __shfl_xor(sm, m, 32);
        const float attv = (j < lenS) ? e * vrcp(sm) : 0.f;
        if (w == 0 && j < K_) out_att[gsS * K_ + j] = attv;

        // weighted sum: wave w covers dims [32w,32w+32) for both samples
        const int d = w * 32 + (lane & 31);
        const char* vb2 = (const char*)&vec_s[sp + hh][0][0];
        const int lm = max(lA, lB);
        float sacc = 0.f;
        for (int k = 0; k < lm; ++k) {
            const unsigned short u = *(const unsigned short*)(vb2 + k * 256 + ((2 * d) ^ ((k & 7) << 4)));
            const float av = __shfl(attv, k + (lane & 32));
            sacc = fmaf(av, __uint_as_float(((unsigned)u) << 16), sacc);
        }
        wsum_g[gsS * KD_ + d] = f2bf(sacc);
    }
}

// MLP tail on MFMA: 32 samples/block, n-split B-frags in registers.
__global__ __launch_bounds__(256, 3) void cdm_mlp(
    const unsigned short* __restrict__ wsum_g,
    const unsigned short* __restrict__ m1f, const unsigned short* __restrict__ m2f,
    const float* __restrict__ mb1, const float* __restrict__ mb2,
    const float* __restrict__ M3, const float* __restrict__ mb3,
    float* __restrict__ out_scores)
{
    const int tid = threadIdx.x, lane = tid & 63, w = tid >> 6;
    const int S0 = blockIdx.x * 32;

    __shared__ unsigned short h1_s[32][HID_];  // 16 KB, 512B row stride, swizzled
    __shared__ float sc_s[4][32];

    // ---- pass 1: h1 = relu(ws @ M1 + mb1) ----
    short8_t Aw[2][4];
#pragma unroll
    for (int m = 0; m < 2; ++m)
#pragma unroll
        for (int s = 0; s < 4; ++s)
            Aw[m][s] = *(const short8_t*)(wsum_g + (S0 + m * 16 + (lane & 15)) * KD_
                                          + s * 32 + (lane >> 4) * 8);
    short8_t B1r[4][4];
    {
        const short8_t* bf1 = (const short8_t*)m1f;
#pragma unroll
        for (int nn = 0; nn < 4; ++nn)
#pragma unroll
            for (int s = 0; s < 4; ++s)
                B1r[nn][s] = bf1[((w * 4 + nn) * 4 + s) * 64 + lane];
    }
#pragma unroll
    for (int nn = 0; nn < 4; ++nn) {
        f32x4 c0 = {0.f, 0.f, 0.f, 0.f}, c1 = {0.f, 0.f, 0.f, 0.f};
#pragma unroll
        for (int s = 0; s < 4; ++s) {
            c0 = __builtin_amdgcn_mfma_f32_16x16x32_bf16(Aw[0][s], B1r[nn][s], c0, 0, 0, 0);
            c1 = __builtin_amdgcn_mfma_f32_16x16x32_bf16(Aw[1][s], B1r[nn][s], c1, 0, 0, 0);
        }
        const int col = (w * 4 + nn) * 16 + (lane & 15);
        const float bias = mb1[col];
#pragma unroll
        for (int i = 0; i < 4; ++i) {
            const int r0 = (lane >> 4) * 4 + i;
            const int r1 = 16 + r0;
            *(unsigned short*)((char*)h1_s + r0 * 512 + ((2 * col) ^ ((r0 & 7) << 4)))
                = f2bf(fmaxf(c0[i] + bias, 0.f));
            *(unsigned short*)((char*)h1_s + r1 * 512 + ((2 * col) ^ ((r0 & 7) << 4)))
                = f2bf(fmaxf(c1[i] + bias, 0.f));
        }
    }
    __syncthreads();

    // ---- pass 2: h2 = relu(h1 @ M2 + mb2), fused M3 dot ----
    short8_t B2r[2][8];
    {
        const short8_t* bf2 = (const short8_t*)m2f;
#pragma unroll
        for (int nn = 0; nn < 2; ++nn)
#pragma unroll
            for (int s = 0; s < 8; ++s)
                B2r[nn][s] = bf2[((w * 2 + nn) * 8 + s) * 64 + lane];
    }
    f32x4 d00 = {0.f, 0.f, 0.f, 0.f}, d01 = {0.f, 0.f, 0.f, 0.f};
    f32x4 d10 = {0.f, 0.f, 0.f, 0.f}, d11 = {0.f, 0.f, 0.f, 0.f};
    {
        const int lr = lane & 15;
#pragma unroll
        for (int s = 0; s < 8; ++s) {
            const int off = (s * 64 + (lane >> 4) * 16) ^ ((lr & 7) << 4);
            const short8_t Ah0 = *(const short8_t*)((const char*)h1_s + lr * 512 + off);
            const short8_t Ah1 = *(const short8_t*)((const char*)h1_s + (16 + lr) * 512 + off);
            d00 = __builtin_amdgcn_mfma_f32_16x16x32_bf16(Ah0, B2r[0][s], d00, 0, 0, 0);
            d01 = __builtin_amdgcn_mfma_f32_16x16x32_bf16(Ah0, B2r[1][s], d01, 0, 0, 0);
            d10 = __builtin_amdgcn_mfma_f32_16x16x32_bf16(Ah1, B2r[0][s], d10, 0, 0, 0);
            d11 = __builtin_amdgcn_mfma_f32_16x16x32_bf16(Ah1, B2r[1][s], d11, 0, 0, 0);
        }
    }
    float part0[4] = {0, 0, 0, 0}, part1[4] = {0, 0, 0, 0};
#pragma unroll
    for (int nn = 0; nn < 2; ++nn) {
        const int col = (w * 2 + nn) * 16 + (lane & 15);
        const float bb = mb2[col], m3v = M3[col];
        const f32x4 dm0 = nn ? d01 : d00;
        const f32x4 dm1 = nn ? d11 : d10;
#pragma unroll
        for (int i = 0; i < 4; ++i) {
            part0[i] = fmaf(fmaxf(dm0[i] + bb, 0.f), m3v, part0[i]);
            part1[i] = fmaf(fmaxf(dm1[i] + bb, 0.f), m3v, part1[i]);
        }
    }
#pragma unroll
    for (int i = 0; i < 4; ++i) {
#pragma unroll
        for (int m = 1; m <= 8; m <<= 1) {
            part0[i] += __shfl_xor(part0[i], m);
            part1[i] += __shfl_xor(part1[i], m);
        }
    }
    if ((lane & 15) == 0) {
        const int g = lane >> 4;
#pragma unroll
        for (int i = 0; i < 4; ++i) {
            sc_s[w][g * 4 + i] = part0[i];
            sc_s[w][16 + g * 4 + i] = part1[i];
        }
    }
    __syncthreads();
    if (tid < 32) {
        const float sc = sc_s[0][tid] + sc_s[1][tid] + sc_s[2][tid] + sc_s[3][tid] + mb3[0];
        out_scores[S0 + tid] = 1.f / (1.f + __expf(-sc));
    }
}

extern "C" void kernel_launch(void* const* d_in, const int* in_sizes, int n_in,
                              void* d_out, int out_size, void* d_ws, size_t ws_size,
                              hipStream_t stream) {
    const int*   stu = (const int*)d_in[0];
    const int*   kpi = (const int*)d_in[1];
    const int*   kpl = (const int*)d_in[2];
    const float* emb = (const float*)d_in[3];
    const float* W1  = (const float*)d_in[4];
    const float* b1  = (const float*)d_in[5];
    const float* w2  = (const float*)d_in[6];
    const float* b2  = (const float*)d_in[7];
    const float* M1  = (const float*)d_in[8];
    const float* mb1 = (const float*)d_in[9];
    const float* M2  = (const float*)d_in[10];
    const float* mb2 = (const float*)d_in[11];
    const float* M3  = (const float*)d_in[12];
    const float* mb3 = (const float*)d_in[13];
    const int B = in_sizes[0];

    float* out_scores = (float*)d_out;
    float* out_att    = out_scores + B;

    unsigned short* w1f  = (unsigned short*)d_ws;       // 64 KB
    unsigned short* m1f  = w1f + 32768;                 // 64 KB
    unsigned short* m2f  = m1f + 32768;                 // 64 KB
    unsigned short* wsum = m2f + 32768;                 // B*128 bf16 = 4 MB

    prep_frags<<<384, 256, 0, stream>>>(W1, M1, M2, w1f, m1f, m2f);
    cdm_attn<<<B / 8, 256, 0, stream>>>(stu, kpi, kpl, emb, w1f, b1, w2, b2,
                                        out_att, wsum);
    cdm_mlp<<<B / 32, 256, 0, stream>>>(wsum, m1f, m2f, mb1, mb2, M3, mb3, out_scores);
}